// Round 1
// baseline (260.016 us; speedup 1.0000x reference)
//
#include <hip/hip_runtime.h>
#include <stdint.h>

#define SEQ    4096
#define EMBED  1024
#define NHEAD  16
#define HDIM   64
#define WIN    256
#define BSZ    2
#define M_TOT  (BSZ * SEQ)   // 8192
#define N_QKV  3072
#define K_DIM  1024

typedef __attribute__((ext_vector_type(8))) __bf16 bf16x8;
typedef __attribute__((ext_vector_type(4))) float  f32x4;

__device__ __forceinline__ unsigned short f2bf(float f) {
  union { float f; unsigned int u; } c; c.f = f;
  unsigned int u = c.u;
  unsigned int r = (u + 0x7FFFu + ((u >> 16) & 1u)) >> 16;
  return (unsigned short)r;
}

__device__ __forceinline__ void gl2lds16(const void* g, void* l) {
  __builtin_amdgcn_global_load_lds((const __attribute__((address_space(1))) void*)g,
                                   (__attribute__((address_space(3))) void*)l, 16, 0, 0);
}

// ---------------- fp32 -> bf16 cast of hidden_states ----------------
__global__ __launch_bounds__(256) void cvt_h(const float* __restrict__ in,
                                             unsigned short* __restrict__ out) {
  int i = (blockIdx.x * 256 + threadIdx.x) * 4;
  float4 v = *(const float4*)(in + i);
  ushort4 o;
  o.x = f2bf(v.x); o.y = f2bf(v.y); o.z = f2bf(v.z); o.w = f2bf(v.w);
  *(ushort4*)(out + i) = o;
}

// ------- transpose + cast weights: Wt[n_global][k] = W_sel[k][n] -------
__global__ __launch_bounds__(256) void cvt_w(const float* __restrict__ Wq,
                                             const float* __restrict__ Wk,
                                             const float* __restrict__ Wv,
                                             unsigned short* __restrict__ Wt) {
  __shared__ float t[32][33];
  int z = blockIdx.z;
  const float* W = (z == 0) ? Wq : (z == 1) ? Wk : Wv;
  int kb = blockIdx.x * 32, nb = blockIdx.y * 32;
  int tx = threadIdx.x, ty = threadIdx.y;  // block (32,8)
  for (int it = 0; it < 4; ++it) {
    int k = kb + ty + it * 8;
    t[ty + it * 8][tx] = W[(size_t)k * 1024 + nb + tx];
  }
  __syncthreads();
  for (int it = 0; it < 4; ++it) {
    int n = nb + ty + it * 8;
    Wt[(size_t)(z * 1024 + n) * 1024 + kb + tx] = f2bf(t[tx][ty + it * 8]);
  }
}

// ---------------- fused QKV GEMM: [8192,1024] x [1024,3072] ----------------
__global__ __launch_bounds__(256) void qkv_gemm(const unsigned short* __restrict__ A,   // h bf16 [8192][1024]
                                                const unsigned short* __restrict__ Bt,  // Wt [3072][1024]
                                                const float* __restrict__ bq,
                                                const float* __restrict__ bk,
                                                const float* __restrict__ bv,
                                                unsigned short* __restrict__ C) {       // qkv [8192][3072]
  __shared__ unsigned short As[128 * 32];
  __shared__ unsigned short Bs[128 * 32];
  int tid  = threadIdx.x;
  int lane = tid & 63, wave = tid >> 6;
  int ln   = lane & 15, quad = lane >> 4;
  int m0 = blockIdx.y * 128, n0 = blockIdx.x * 128;
  int wy = wave >> 1, wx = wave & 1;
  f32x4 acc[4][4];
  for (int i = 0; i < 4; ++i)
    for (int j = 0; j < 4; ++j) acc[i][j] = (f32x4){0.f, 0.f, 0.f, 0.f};

  for (int k0 = 0; k0 < K_DIM; k0 += 32) {
    __syncthreads();
    for (int it = 0; it < 2; ++it) {
      int chunk = wave * 128 + it * 64 + lane;
      int row = chunk >> 2, cb = chunk & 3;
      gl2lds16(A + (size_t)(m0 + row) * K_DIM + k0 + cb * 8,
               As + (size_t)(wave * 128 + it * 64) * 8);
    }
    for (int it = 0; it < 2; ++it) {
      int chunk = wave * 128 + it * 64 + lane;
      int row = chunk >> 2, cb = chunk & 3;
      gl2lds16(Bt + (size_t)(n0 + row) * K_DIM + k0 + cb * 8,
               Bs + (size_t)(wave * 128 + it * 64) * 8);
    }
    __syncthreads();
    bf16x8 af[4], bfr[4];
    for (int i = 0; i < 4; ++i)
      af[i] = *(const bf16x8*)&As[(wy * 64 + i * 16 + ln) * 32 + quad * 8];
    for (int j = 0; j < 4; ++j)
      bfr[j] = *(const bf16x8*)&Bs[(wx * 64 + j * 16 + ln) * 32 + quad * 8];
    for (int i = 0; i < 4; ++i)
      for (int j = 0; j < 4; ++j)
        acc[i][j] = __builtin_amdgcn_mfma_f32_16x16x32_bf16(af[i], bfr[j], acc[i][j], 0, 0, 0);
  }

  for (int j = 0; j < 4; ++j) {
    int n = n0 + wx * 64 + j * 16 + ln;
    float bias, scl;
    if (n < 1024)      { bias = bq[n];        scl = 0.125f; }
    else if (n < 2048) { bias = bk[n - 1024]; scl = 1.f; }
    else               { bias = bv[n - 2048]; scl = 1.f; }
    for (int i = 0; i < 4; ++i) {
      int mb = m0 + wy * 64 + i * 16 + quad * 4;
      for (int r = 0; r < 4; ++r) {
        float v = (acc[i][j][r] + bias) * scl;
        C[(size_t)(mb + r) * N_QKV + n] = f2bf(v);
      }
    }
  }
}

// ---------------- banded flash attention ----------------
__global__ __launch_bounds__(256) void attn(const unsigned short* __restrict__ qkv,
                                            float* __restrict__ out) {
  __shared__ unsigned short Ql[64 * 72];
  __shared__ unsigned short Kl[64 * 72];
  __shared__ unsigned short Vt[64 * 72];
  __shared__ unsigned short Pl[64 * 72];
  int tid  = threadIdx.x;
  int lane = tid & 63, wave = tid >> 6;
  int ln   = lane & 15, quad = lane >> 4;
  int qb = blockIdx.x, head = blockIdx.y, b = blockIdx.z;
  int q0 = qb * 64;
  size_t baseRow = (size_t)b * SEQ;

  // stage Q (already scaled by 1/8 in GEMM epilogue)
  for (int it = 0; it < 2; ++it) {
    int idx = it * 256 + tid;
    int y = idx >> 3, c = idx & 7;
    uint4 v = *(const uint4*)&qkv[(baseRow + q0 + y) * N_QKV + head * HDIM + c * 8];
    *(uint4*)&Ql[y * 72 + c * 8] = v;
  }
  __syncthreads();
  bf16x8 qa[2];
  qa[0] = *(const bf16x8*)&Ql[(wave * 16 + ln) * 72 + 0  + quad * 8];
  qa[1] = *(const bf16x8*)&Ql[(wave * 16 + ln) * 72 + 32 + quad * 8];

  float m_st[4], l_st[4];
  f32x4 o4[4];
  for (int r = 0; r < 4; ++r) { m_st[r] = -INFINITY; l_st[r] = 0.f; }
  for (int d = 0; d < 4; ++d) o4[d] = (f32x4){0.f, 0.f, 0.f, 0.f};

  for (int jt = 0; jt < 9; ++jt) {
    int kt = q0 - WIN + jt * 64;
    if (kt <= -64 || kt >= SEQ) continue;  // uniform across block
    __syncthreads();
    // stage K tile and V^T tile (zero-fill OOB rows)
    for (int it = 0; it < 2; ++it) {
      int idx = it * 256 + tid;
      int y = idx >> 3, c = idx & 7;
      int kpos = kt + y;
      uint4 vK = {0, 0, 0, 0}, vV = {0, 0, 0, 0};
      if (kpos >= 0 && kpos < SEQ) {
        size_t ro = (baseRow + kpos) * N_QKV + head * HDIM + c * 8;
        vK = *(const uint4*)&qkv[ro + 1024];
        vV = *(const uint4*)&qkv[ro + 2048];
      }
      *(uint4*)&Kl[y * 72 + c * 8] = vK;
      const unsigned short* e = (const unsigned short*)&vV;
      for (int j = 0; j < 8; ++j) Vt[(c * 8 + j) * 72 + y] = e[j];
    }
    __syncthreads();

    // S = Q K^T  (16 queries/wave x 64 keys)
    f32x4 s[4];
    for (int nt = 0; nt < 4; ++nt) {
      s[nt] = (f32x4){0.f, 0.f, 0.f, 0.f};
      for (int ks = 0; ks < 2; ++ks) {
        bf16x8 kb = *(const bf16x8*)&Kl[(nt * 16 + ln) * 72 + ks * 32 + quad * 8];
        s[nt] = __builtin_amdgcn_mfma_f32_16x16x32_bf16(qa[ks], kb, s[nt], 0, 0, 0);
      }
    }
    // mask: band +/- WIN and sequence bounds
    int qpb = q0 + wave * 16 + quad * 4;
    for (int nt = 0; nt < 4; ++nt) {
      int kpos = kt + nt * 16 + ln;
      bool okk = (kpos >= 0) && (kpos < SEQ);
      for (int r = 0; r < 4; ++r) {
        int dd = kpos - (qpb + r);
        if (!okk || dd < -WIN || dd > WIN) s[nt][r] = -INFINITY;
      }
    }
    // online softmax
    float tm[4];
    for (int r = 0; r < 4; ++r)
      tm[r] = fmaxf(fmaxf(s[0][r], s[1][r]), fmaxf(s[2][r], s[3][r]));
    for (int off = 1; off < 16; off <<= 1)
      for (int r = 0; r < 4; ++r) tm[r] = fmaxf(tm[r], __shfl_xor(tm[r], off));
    float alpha[4], msafe[4];
    for (int r = 0; r < 4; ++r) {
      float mn = fmaxf(m_st[r], tm[r]);
      msafe[r] = (mn == -INFINITY) ? 0.f : mn;
      alpha[r] = __expf(m_st[r] - msafe[r]);  // -inf state -> 0
      m_st[r]  = mn;
    }
    float rs[4] = {0.f, 0.f, 0.f, 0.f};
    for (int nt = 0; nt < 4; ++nt)
      for (int r = 0; r < 4; ++r) {
        float p = __expf(s[nt][r] - msafe[r]);  // masked -> 0
        s[nt][r] = p;
        rs[r] += p;
      }
    for (int off = 1; off < 16; off <<= 1)
      for (int r = 0; r < 4; ++r) rs[r] += __shfl_xor(rs[r], off);
    for (int r = 0; r < 4; ++r) l_st[r] = l_st[r] * alpha[r] + rs[r];

    // P -> LDS (C-layout -> A-layout round trip)
    for (int nt = 0; nt < 4; ++nt)
      for (int r = 0; r < 4; ++r)
        Pl[(wave * 16 + quad * 4 + r) * 72 + nt * 16 + ln] = f2bf(s[nt][r]);
    for (int d = 0; d < 4; ++d)
      for (int r = 0; r < 4; ++r) o4[d][r] *= alpha[r];
    __syncthreads();

    // O += P V
    for (int ks = 0; ks < 2; ++ks) {
      bf16x8 pa = *(const bf16x8*)&Pl[(wave * 16 + ln) * 72 + ks * 32 + quad * 8];
      for (int d = 0; d < 4; ++d) {
        bf16x8 vb = *(const bf16x8*)&Vt[(d * 16 + ln) * 72 + ks * 32 + quad * 8];
        o4[d] = __builtin_amdgcn_mfma_f32_16x16x32_bf16(pa, vb, o4[d], 0, 0, 0);
      }
    }
  }

  for (int d = 0; d < 4; ++d)
    for (int r = 0; r < 4; ++r) {
      int qpos = q0 + wave * 16 + quad * 4 + r;
      out[(baseRow + qpos) * EMBED + head * HDIM + d * 16 + ln] = o4[d][r] / l_st[r];
    }
}

extern "C" void kernel_launch(void* const* d_in, const int* in_sizes, int n_in,
                              void* d_out, int out_size, void* d_ws, size_t ws_size,
                              hipStream_t stream) {
  const float* h  = (const float*)d_in[0];
  const float* Wq = (const float*)d_in[1];
  const float* bq = (const float*)d_in[2];
  const float* Wk = (const float*)d_in[3];
  const float* bk = (const float*)d_in[4];
  const float* Wv = (const float*)d_in[5];
  const float* bv = (const float*)d_in[6];
  float* out = (float*)d_out;

  unsigned short* h_bf  = (unsigned short*)d_ws;                 // 16 MB
  unsigned short* wt_bf = h_bf + (size_t)M_TOT * K_DIM;          //  6 MB
  unsigned short* qkv   = wt_bf + (size_t)N_QKV * K_DIM;         // 48 MB

  cvt_h<<<(M_TOT * K_DIM) / 1024, 256, 0, stream>>>(h, h_bf);
  cvt_w<<<dim3(32, 32, 3), dim3(32, 8), 0, stream>>>(Wq, Wk, Wv, wt_bf);
  qkv_gemm<<<dim3(N_QKV / 128, M_TOT / 128), 256, 0, stream>>>(h_bf, wt_bf, bq, bk, bv, qkv);
  attn<<<dim3(SEQ / 64, NHEAD, BSZ), 256, 0, stream>>>(qkv, out);
}

// Round 3
// 237.843 us; speedup vs baseline: 1.0932x; 1.0932x over previous
//
#include <hip/hip_runtime.h>
#include <stdint.h>

#define SEQ    4096
#define EMBED  1024
#define NHEAD  16
#define HDIM   64
#define WIN    256
#define BSZ    2
#define M_TOT  (BSZ * SEQ)   // 8192
#define N_QKV  3072
#define N_QK   2048
#define K_DIM  1024
#define LOG2E  1.4426950408889634f

typedef __attribute__((ext_vector_type(8))) __bf16 bf16x8;
typedef __attribute__((ext_vector_type(4))) float  f32x4;

__device__ __forceinline__ unsigned short f2bf(float f) {
  union { float f; unsigned int u; } c; c.f = f;
  unsigned int u = c.u;
  unsigned int r = (u + 0x7FFFu + ((u >> 16) & 1u)) >> 16;
  return (unsigned short)r;
}

__device__ __forceinline__ void gl2lds16(const void* g, void* l) {
  __builtin_amdgcn_global_load_lds((const __attribute__((address_space(1))) void*)g,
                                   (__attribute__((address_space(3))) void*)l, 16, 0, 0);
}

// ---------------- fp32 -> bf16 cast of hidden_states ----------------
__global__ __launch_bounds__(256) void cvt_h(const float* __restrict__ in,
                                             unsigned short* __restrict__ out) {
  int i = (blockIdx.x * 256 + threadIdx.x) * 4;
  float4 v = *(const float4*)(in + i);
  ushort4 o;
  o.x = f2bf(v.x); o.y = f2bf(v.y); o.z = f2bf(v.z); o.w = f2bf(v.w);
  *(ushort4*)(out + i) = o;
}

// ------- transpose + cast weights: Wt[n_global][k] = W_sel[k][n] -------
__global__ __launch_bounds__(256) void cvt_w(const float* __restrict__ Wq,
                                             const float* __restrict__ Wk,
                                             const float* __restrict__ Wv,
                                             unsigned short* __restrict__ Wt) {
  __shared__ float t[32][33];
  int z = blockIdx.z;
  const float* W = (z == 0) ? Wq : (z == 1) ? Wk : Wv;
  int kb = blockIdx.x * 32, nb = blockIdx.y * 32;
  int tx = threadIdx.x, ty = threadIdx.y;  // block (32,8)
  for (int it = 0; it < 4; ++it) {
    int k = kb + ty + it * 8;
    t[ty + it * 8][tx] = W[(size_t)k * 1024 + nb + tx];
  }
  __syncthreads();
  for (int it = 0; it < 4; ++it) {
    int n = nb + ty + it * 8;
    Wt[(size_t)(z * 1024 + n) * 1024 + kb + tx] = f2bf(t[tx][ty + it * 8]);
  }
}

// ---- fused QKV GEMM: [8192,1024] x [1024,3072]; Q/K -> qk[m][2048], V -> vtg[b*1024+hd][4096]
__global__ __launch_bounds__(256) void qkv_gemm(const unsigned short* __restrict__ A,   // h bf16 [8192][1024]
                                                const unsigned short* __restrict__ Bt,  // Wt [3072][1024]
                                                const float* __restrict__ bq,
                                                const float* __restrict__ bk,
                                                const float* __restrict__ bv,
                                                unsigned short* __restrict__ C,         // qk [8192][2048]
                                                unsigned short* __restrict__ Vt) {      // vtg [2048][4096]
  __shared__ unsigned short As[128 * 32];
  __shared__ unsigned short Bs[128 * 32];
  int tid  = threadIdx.x;
  int lane = tid & 63, wave = tid >> 6;
  int ln   = lane & 15, quad = lane >> 4;
  int m0 = blockIdx.y * 128, n0 = blockIdx.x * 128;
  int wy = wave >> 1, wx = wave & 1;
  f32x4 acc[4][4];
  for (int i = 0; i < 4; ++i)
    for (int j = 0; j < 4; ++j) acc[i][j] = (f32x4){0.f, 0.f, 0.f, 0.f};

  for (int k0 = 0; k0 < K_DIM; k0 += 32) {
    __syncthreads();
    for (int it = 0; it < 2; ++it) {
      int chunk = wave * 128 + it * 64 + lane;
      int row = chunk >> 2, cb = chunk & 3;
      gl2lds16(A + (size_t)(m0 + row) * K_DIM + k0 + cb * 8,
               As + (size_t)(wave * 128 + it * 64) * 8);
    }
    for (int it = 0; it < 2; ++it) {
      int chunk = wave * 128 + it * 64 + lane;
      int row = chunk >> 2, cb = chunk & 3;
      gl2lds16(Bt + (size_t)(n0 + row) * K_DIM + k0 + cb * 8,
               Bs + (size_t)(wave * 128 + it * 64) * 8);
    }
    __syncthreads();
    bf16x8 af[4], bfr[4];
    for (int i = 0; i < 4; ++i)
      af[i] = *(const bf16x8*)&As[(wy * 64 + i * 16 + ln) * 32 + quad * 8];
    for (int j = 0; j < 4; ++j)
      bfr[j] = *(const bf16x8*)&Bs[(wx * 64 + j * 16 + ln) * 32 + quad * 8];
    for (int i = 0; i < 4; ++i)
      for (int j = 0; j < 4; ++j)
        acc[i][j] = __builtin_amdgcn_mfma_f32_16x16x32_bf16(af[i], bfr[j], acc[i][j], 0, 0, 0);
  }

  if (n0 < N_QK) {
    for (int j = 0; j < 4; ++j) {
      int n = n0 + wx * 64 + j * 16 + ln;
      float bias, scl;
      if (n < 1024) { bias = bq[n];        scl = 0.125f * LOG2E; }  // fold 1/sqrt(64) and log2(e)
      else          { bias = bk[n - 1024]; scl = 1.f; }
      for (int i = 0; i < 4; ++i) {
        int mb = m0 + wy * 64 + i * 16 + quad * 4;
        for (int r = 0; r < 4; ++r) {
          float v = (acc[i][j][r] + bias) * scl;
          C[(size_t)(mb + r) * N_QK + n] = f2bf(v);
        }
      }
    }
  } else {
    for (int j = 0; j < 4; ++j) {
      int n  = n0 + wx * 64 + j * 16 + ln;   // 2048..3071
      int hd = n - 2048;                     // head*64 + d
      float bias = bv[hd];
      for (int i = 0; i < 4; ++i) {
        int mb  = m0 + wy * 64 + i * 16 + quad * 4;
        int bb  = mb >> 12;                  // / SEQ
        int pos = mb & (SEQ - 1);
        ushort4 pk;
        pk.x = f2bf(acc[i][j][0] + bias);
        pk.y = f2bf(acc[i][j][1] + bias);
        pk.z = f2bf(acc[i][j][2] + bias);
        pk.w = f2bf(acc[i][j][3] + bias);
        *(ushort4*)&Vt[((size_t)bb * (NHEAD * HDIM) + hd) * SEQ + pos] = pk;
      }
    }
  }
}

// ---------------- banded flash attention, 128 queries / block ----------------
__global__ __launch_bounds__(256) void attn(const unsigned short* __restrict__ qk,
                                            const unsigned short* __restrict__ vtg,
                                            float* __restrict__ out) {
  __shared__ unsigned short Kl[64 * 72];
  __shared__ unsigned short Vl[64 * 72];
  __shared__ unsigned short Pl[128 * 72];
  int tid  = threadIdx.x;
  int lane = tid & 63, wave = tid >> 6;
  int ln   = lane & 15, quad = lane >> 4;
  int q0 = blockIdx.x * 128, head = blockIdx.y, b = blockIdx.z;
  size_t baseRow = (size_t)b * SEQ;
  const unsigned short* kptr = qk + 1024;
  const unsigned short* vrow = vtg + ((size_t)(b * NHEAD + head) * HDIM) * SEQ;

  // Q fragments straight from global (B-operand layout: n = q = ln, k = ks*32 + quad*8 + j)
  bf16x8 qf[2][2];
  for (int i = 0; i < 2; ++i) {
    size_t ro = (baseRow + q0 + wave * 32 + i * 16 + ln) * (size_t)N_QK + head * HDIM + quad * 8;
    qf[i][0] = *(const bf16x8*)&qk[ro];
    qf[i][1] = *(const bf16x8*)&qk[ro + 32];
  }

  float m_st[2] = {-INFINITY, -INFINITY};
  float l_st[2] = {0.f, 0.f};
  f32x4 o_acc[2][4];
  for (int i = 0; i < 2; ++i)
    for (int dt = 0; dt < 4; ++dt) o_acc[i][dt] = (f32x4){0.f, 0.f, 0.f, 0.f};

  for (int jt = 0; jt < 10; ++jt) {
    int kt = q0 - 256 + jt * 64;
    if (kt < 0 || kt >= SEQ) continue;      // block-uniform
    __syncthreads();
    for (int it = 0; it < 2; ++it) {
      int idx = it * 256 + tid;
      int y = idx >> 3, c = idx & 7;
      uint4 vK = *(const uint4*)&kptr[(baseRow + kt + y) * (size_t)N_QK + head * HDIM + c * 8];
      uint4 vV = *(const uint4*)&vrow[(size_t)y * SEQ + kt + c * 8];
      *(uint4*)&Kl[y * 72 + c * 8] = vK;
      *(uint4*)&Vl[y * 72 + c * 8] = vV;
    }
    __syncthreads();

    // S^T = K Q^T : rows kpos = kt + nt*16 + quad*4 + r, col q = ln (per i-tile)
    bf16x8 kf[4][2];
    for (int nt = 0; nt < 4; ++nt)
      for (int ks = 0; ks < 2; ++ks)
        kf[nt][ks] = *(const bf16x8*)&Kl[(nt * 16 + ln) * 72 + ks * 32 + quad * 8];
    f32x4 s[2][4];
    for (int i = 0; i < 2; ++i)
      for (int nt = 0; nt < 4; ++nt) {
        f32x4 z = (f32x4){0.f, 0.f, 0.f, 0.f};
        z = __builtin_amdgcn_mfma_f32_16x16x32_bf16(kf[nt][0], qf[i][0], z, 0, 0, 0);
        z = __builtin_amdgcn_mfma_f32_16x16x32_bf16(kf[nt][1], qf[i][1], z, 0, 0, 0);
        s[i][nt] = z;
      }

    int o = kt - q0;
    if (o <= -192 || o >= 256) {            // only edge tiles need the band mask
      for (int i = 0; i < 2; ++i) {
        int qq = q0 + wave * 32 + i * 16 + ln;
        for (int nt = 0; nt < 4; ++nt) {
          int kbase = kt + nt * 16 + quad * 4 - qq;
          for (int r = 0; r < 4; ++r) {
            int dd = kbase + r;
            if (dd < -WIN || dd > WIN) s[i][nt][r] = -INFINITY;
          }
        }
      }
    }

    // online softmax per q (= column = ln); scores already in log2 units
    float alpha_s[2];
    for (int i = 0; i < 2; ++i) {
      float tm = s[i][0][0];
      for (int nt = 0; nt < 4; ++nt)
        for (int r = 0; r < 4; ++r) tm = fmaxf(tm, s[i][nt][r]);
      tm = fmaxf(tm, __shfl_xor(tm, 16));
      tm = fmaxf(tm, __shfl_xor(tm, 32));
      float mn = fmaxf(m_st[i], tm);
      float msafe = (mn == -INFINITY) ? 0.f : mn;
      float alpha = exp2f(m_st[i] - msafe);
      m_st[i] = mn;
      float rs = 0.f;
      for (int nt = 0; nt < 4; ++nt)
        for (int r = 0; r < 4; ++r) {
          float p = exp2f(s[i][nt][r] - msafe);
          s[i][nt][r] = p;
          rs += p;
        }
      rs += __shfl_xor(rs, 16);
      rs += __shfl_xor(rs, 32);
      l_st[i] = l_st[i] * alpha + rs;
      alpha_s[i] = alpha;
    }

    // P write: lane holds 4 consecutive kpos for q=ln -> packed 8B store (wave-private region)
    for (int i = 0; i < 2; ++i)
      for (int nt = 0; nt < 4; ++nt) {
        ushort4 pk;
        pk.x = f2bf(s[i][nt][0]);
        pk.y = f2bf(s[i][nt][1]);
        pk.z = f2bf(s[i][nt][2]);
        pk.w = f2bf(s[i][nt][3]);
        *(ushort4*)&Pl[(wave * 32 + i * 16 + ln) * 72 + nt * 16 + quad * 4] = pk;
      }

    // rescale O (rows q = quad*4+r) by alpha (indexed by q=ln) via broadcast shuffle
    for (int i = 0; i < 2; ++i) {
      float af[4];
      for (int r = 0; r < 4; ++r)
        af[r] = __shfl(alpha_s[i], (lane & 48) | (quad * 4 + r));
      for (int dt = 0; dt < 4; ++dt)
        for (int r = 0; r < 4; ++r) o_acc[i][dt][r] *= af[r];
    }

    // O += P V : A = P [q][kk] (wave-private rows), B = V [kk][d] from V^T tile
    bf16x8 vf[4][2];
    for (int dt = 0; dt < 4; ++dt)
      for (int ks = 0; ks < 2; ++ks)
        vf[dt][ks] = *(const bf16x8*)&Vl[(dt * 16 + ln) * 72 + ks * 32 + quad * 8];
    for (int i = 0; i < 2; ++i)
      for (int ks = 0; ks < 2; ++ks) {
        bf16x8 pf = *(const bf16x8*)&Pl[(wave * 32 + i * 16 + ln) * 72 + ks * 32 + quad * 8];
        for (int dt = 0; dt < 4; ++dt)
          o_acc[i][dt] = __builtin_amdgcn_mfma_f32_16x16x32_bf16(pf, vf[dt][ks], o_acc[i][dt], 0, 0, 0);
      }
  }

  for (int i = 0; i < 2; ++i) {
    float li[4];
    for (int r = 0; r < 4; ++r)
      li[r] = __shfl(l_st[i], (lane & 48) | (quad * 4 + r));
    for (int dt = 0; dt < 4; ++dt)
      for (int r = 0; r < 4; ++r) {
        int qpos = q0 + wave * 32 + i * 16 + quad * 4 + r;
        out[(baseRow + qpos) * (size_t)EMBED + head * HDIM + dt * 16 + ln] =
            o_acc[i][dt][r] / li[r];
      }
  }
}

extern "C" void kernel_launch(void* const* d_in, const int* in_sizes, int n_in,
                              void* d_out, int out_size, void* d_ws, size_t ws_size,
                              hipStream_t stream) {
  const float* h  = (const float*)d_in[0];
  const float* Wq = (const float*)d_in[1];
  const float* bq = (const float*)d_in[2];
  const float* Wk = (const float*)d_in[3];
  const float* bk = (const float*)d_in[4];
  const float* Wv = (const float*)d_in[5];
  const float* bv = (const float*)d_in[6];
  float* out = (float*)d_out;

  unsigned short* h_bf  = (unsigned short*)d_ws;                 // 16 MB
  unsigned short* wt_bf = h_bf + (size_t)M_TOT * K_DIM;          //  6 MB
  unsigned short* qk    = wt_bf + (size_t)N_QKV * K_DIM;         // 32 MB
  unsigned short* vtg   = qk + (size_t)M_TOT * N_QK;             // 16 MB  (total 70 MB)

  cvt_h<<<(M_TOT * K_DIM) / 1024, 256, 0, stream>>>(h, h_bf);
  cvt_w<<<dim3(32, 32, 3), dim3(32, 8), 0, stream>>>(Wq, Wk, Wv, wt_bf);
  qkv_gemm<<<dim3(N_QKV / 128, M_TOT / 128), 256, 0, stream>>>(h_bf, wt_bf, bq, bk, bv, qk, vtg);
  attn<<<dim3(SEQ / 128, NHEAD, BSZ), 256, 0, stream>>>(qk, vtg, out);
}